// Round 8
// baseline (226.018 us; speedup 1.0000x reference)
//
#include <hip/hip_runtime.h>
#include <hip/hip_fp16.h>

#define N_NODES_C 50000
#define N_EDGES_C 800000
#define K_FEAT 128
#define HM_STRIDE 256  // [h(128) | mean(128)] fp16 per node
#define NB_C 196       // coarse buckets / edge blocks (196*4096 >= 800000; 50000 <= 196*256)

typedef unsigned int uint_t;
typedef _Float16 half8 __attribute__((ext_vector_type(8)));
typedef _Float16 half4 __attribute__((ext_vector_type(4)));
typedef float f32x4 __attribute__((ext_vector_type(4)));

// ================= CSR build via 2-level bucket sort (NO global atomics) =================
// Level 1: coarse bucket = dst>>8 (256 nodes per bucket, 196 used).
// Level 2: within bucket, fine bin = dst&255; global CSR offsets fall out directly.

// P1a: per-block coarse histogram (LDS atomics only).
__global__ __launch_bounds__(256) void p1hist_kernel(const int* __restrict__ dst,
                                                     uint_t* __restrict__ histG, int E) {
    __shared__ uint_t hist[256];
    const int t = threadIdx.x, b = blockIdx.x;
    hist[t] = 0;
    __syncthreads();
    const int base = b * 4096;
#pragma unroll
    for (int j = 0; j < 16; ++j) {
        int idx = base + t + j * 256;
        if (idx < E) atomicAdd(&hist[((uint_t)dst[idx]) >> 8], 1u);
    }
    __syncthreads();
    histG[b * 256 + t] = hist[t];
}

// P1b: single block. histG[b*256+t] -> global slot base for (block b, bin t);
// cbase[t] = start of coarse bucket t; cbase[256] = E.
__global__ __launch_bounds__(256) void p1scan_kernel(uint_t* __restrict__ histG,
                                                     uint_t* __restrict__ cbase, int nb) {
    const int t = threadIdx.x;
    uint_t run = 0;
    for (int b = 0; b < nb; ++b) {  // within-bin prefix over blocks (coalesced per iter)
        uint_t x = histG[b * 256 + t];
        histG[b * 256 + t] = run;
        run += x;
    }
    // block-wide exclusive scan of bin totals
    const int lane = t & 63, wid = t >> 6;
    uint_t x = run;
#pragma unroll
    for (int off = 1; off < 64; off <<= 1) {
        uint_t y = __shfl_up(x, off, 64);
        if (lane >= off) x += y;
    }
    __shared__ uint_t wsum[4];
    if (lane == 63) wsum[wid] = x;
    __syncthreads();
    uint_t wpre = 0;
#pragma unroll
    for (int w = 0; w < 4; ++w)
        if (w < wid) wpre += wsum[w];
    uint_t incl = wpre + x;
    uint_t excl = incl - run;
    cbase[t] = excl;
    if (t == 255) cbase[256] = incl;  // == E
    for (int b = 0; b < nb; ++b) histG[b * 256 + t] += excl;
}

// P1c: scatter packed (fine<<16 | src) into coarse-bucket-contiguous tmp via LDS cursors.
__global__ __launch_bounds__(256) void p1scatter_kernel(const int* __restrict__ src,
                                                        const int* __restrict__ dst,
                                                        const uint_t* __restrict__ histG,
                                                        uint_t* __restrict__ tmp, int E) {
    __shared__ uint_t cur[256];
    const int t = threadIdx.x, b = blockIdx.x;
    cur[t] = histG[b * 256 + t];
    __syncthreads();
    const int base = b * 4096;
#pragma unroll
    for (int j = 0; j < 16; ++j) {
        int idx = base + t + j * 256;
        if (idx < E) {
            uint_t d = (uint_t)dst[idx];
            uint_t s = (uint_t)src[idx];  // < 50000 < 2^16
            uint_t slot = atomicAdd(&cur[d >> 8], 1u);
            tmp[slot] = ((d & 255u) << 16) | s;
        }
    }
}

// P2: one block per coarse bucket. Fine histogram + LDS scan -> offs; LDS-cursor scatter -> ssrc.
__global__ __launch_bounds__(256) void p2_kernel(const uint_t* __restrict__ tmp,
                                                 const uint_t* __restrict__ cbase,
                                                 int* __restrict__ offs, int* __restrict__ ssrc) {
    __shared__ uint_t hist[256];
    __shared__ uint_t cur[256];
    __shared__ uint_t wsum[4];
    const int t = threadIdx.x, c = blockIdx.x;
    const uint_t cb = cbase[c], ce = cbase[c + 1];
    hist[t] = 0;
    __syncthreads();
    for (uint_t i = cb + t; i < ce; i += 256) atomicAdd(&hist[tmp[i] >> 16], 1u);
    __syncthreads();
    const uint_t v = hist[t];
    const int lane = t & 63, wid = t >> 6;
    uint_t x = v;
#pragma unroll
    for (int off = 1; off < 64; off <<= 1) {
        uint_t y = __shfl_up(x, off, 64);
        if (lane >= off) x += y;
    }
    if (lane == 63) wsum[wid] = x;
    __syncthreads();
    uint_t wpre = 0;
#pragma unroll
    for (int w = 0; w < 4; ++w)
        if (w < wid) wpre += wsum[w];
    const uint_t excl = wpre + x - v;
    const int node = c * 256 + t;
    if (node < N_NODES_C) offs[node] = (int)(cb + excl);
    if (c == 0 && t == 0) offs[N_NODES_C] = N_EDGES_C;
    cur[t] = excl;
    __syncthreads();
    for (uint_t i = cb + t; i < ce; i += 256) {
        uint_t p = tmp[i];
        uint_t slot = cb + atomicAdd(&cur[p >> 16], 1u);
        ssrc[slot] = (int)(p & 0xFFFFu);
    }
}

// ================= fused convert: features->fp16 hm0 h-part, weights->fp16 transposed =====
// WT[c][k] = Wcat[k][c]; Wcat rows 0..127 = Ws, 128..255 = Wn.

__global__ __launch_bounds__(256) void convert_kernel(
    const float* __restrict__ feat, _Float16* __restrict__ hm0,
    const float* __restrict__ Ws0, const float* __restrict__ Wn0,
    const float* __restrict__ Ws1, const float* __restrict__ Wn1,
    const float* __restrict__ Ws2, const float* __restrict__ Wn2,
    _Float16* __restrict__ WT0, _Float16* __restrict__ WT1, _Float16* __restrict__ WT2) {
    const int i = blockIdx.x * 256 + threadIdx.x;
    const int n4 = N_NODES_C * K_FEAT / 4;  // 1,600,000 float4s
    if (i < n4) {
        float4 v = reinterpret_cast<const float4*>(feat)[i];
        int n = i >> 5, c4 = i & 31;
        half4 o;
        o.x = (_Float16)v.x; o.y = (_Float16)v.y; o.z = (_Float16)v.z; o.w = (_Float16)v.w;
        *reinterpret_cast<half4*>(hm0 + (size_t)n * HM_STRIDE + c4 * 4) = o;
    } else {
        int idx = i - n4;
        if (idx >= 81920) return;
        const float* Ws;
        const float* Wn;
        _Float16* WT;
        int ncol;
        if (idx < 32768) { Ws = Ws0; Wn = Wn0; WT = WT0; ncol = 128; }
        else if (idx < 65536) { idx -= 32768; Ws = Ws1; Wn = Wn1; WT = WT1; ncol = 128; }
        else { idx -= 65536; Ws = Ws2; Wn = Wn2; WT = WT2; ncol = 64; }
        int k = idx & 255, c = idx >> 8;
        float v = (k < 128) ? Ws[(size_t)k * ncol + c] : Wn[(size_t)(k - 128) * ncol + c];
        WT[(size_t)c * 256 + k] = (_Float16)v;
    }
}

// ================= mean aggregation: one wave per node, 4 edge-rows per vmem instr ========

__global__ void mean_kernel(_Float16* __restrict__ hm, const int* __restrict__ offs,
                            const int* __restrict__ ssrc) {
    const int node = (int)((blockIdx.x * blockDim.x + threadIdx.x) >> 6);
    const int lane = threadIdx.x & 63;
    if (node >= N_NODES_C) return;
    const int beg = offs[node], end = offs[node + 1];
    const int g = lane >> 4;
    const int cb = (lane & 15) * 8;
    const _Float16* base = hm + cb;

    float accA[8] = {0.f, 0.f, 0.f, 0.f, 0.f, 0.f, 0.f, 0.f};
    float accB[8] = {0.f, 0.f, 0.f, 0.f, 0.f, 0.f, 0.f, 0.f};

    int e = beg;
    for (; e + 8 <= end; e += 8) {
        const int s0 = ssrc[e + g];
        const int s1 = ssrc[e + 4 + g];
        half8 v0 = *reinterpret_cast<const half8*>(base + (size_t)s0 * HM_STRIDE);
        half8 v1 = *reinterpret_cast<const half8*>(base + (size_t)s1 * HM_STRIDE);
#pragma unroll
        for (int j = 0; j < 8; ++j) accA[j] += (float)v0[j];
#pragma unroll
        for (int j = 0; j < 8; ++j) accB[j] += (float)v1[j];
    }
    for (; e + 4 <= end; e += 4) {
        const int s0 = ssrc[e + g];
        half8 v0 = *reinterpret_cast<const half8*>(base + (size_t)s0 * HM_STRIDE);
#pragma unroll
        for (int j = 0; j < 8; ++j) accA[j] += (float)v0[j];
    }
    if (e < end) {
        const bool valid = (e + g) < end;
        const int s0 = valid ? ssrc[e + g] : ssrc[beg];
        half8 v0 = *reinterpret_cast<const half8*>(base + (size_t)s0 * HM_STRIDE);
        if (valid) {
#pragma unroll
            for (int j = 0; j < 8; ++j) accB[j] += (float)v0[j];
        }
    }

    const float inv = (end > beg) ? 1.0f / (float)(end - beg) : 0.f;
    half8 o;
#pragma unroll
    for (int j = 0; j < 8; ++j) {
        float x = accA[j] + accB[j];
        x += __shfl_xor(x, 16, 64);
        x += __shfl_xor(x, 32, 64);
        o[j] = (_Float16)(x * inv);
    }
    if (lane < 16)
        *reinterpret_cast<half8*>(hm + (size_t)node * HM_STRIDE + 128 + cb) = o;
}

// ================= MFMA GEMM: out = act(hm @ Wcat + b), K=256 =================
// Block: 256 threads (4 waves), 128 rows. WT staged in LDS (XOR-swizzled).
// All 16 A-frags preloaded to registers, then pure LDS+MFMA.
// C/D mapping: col=lane&15, row=(lane>>4)*4+reg (m89-verified).

template <int NCOL, bool ACT, bool OUT_FP32>
__global__ __launch_bounds__(256) void sage_mfma(
    const _Float16* __restrict__ hm,  // [n][256]
    const _Float16* __restrict__ WT,  // [NCOL][256]
    const float* __restrict__ bias,
    float* __restrict__ outf,         // OUT_FP32: [n][NCOL]
    _Float16* __restrict__ outh,      // else: next layer's hm, h-part
    int nNodes) {
    constexpr int CF = NCOL / 16;
    constexpr int RPW = 32;
    constexpr int RPB = 128;

    __shared__ _Float16 bl[NCOL][256];

    const int t = threadIdx.x;
#pragma unroll
    for (int it = 0; it < NCOL * 32 / 256; ++it) {
        int f = t + it * 256;
        int row = f >> 5, c8 = f & 31;
        half8 v = *reinterpret_cast<const half8*>(WT + (size_t)row * 256 + c8 * 8);
        int col = (c8 * 8) ^ ((row & 7) << 3);
        *reinterpret_cast<half8*>(&bl[row][col]) = v;
    }
    __syncthreads();

    const int wid = t >> 6;
    const int lane = t & 63;
    const int r0 = blockIdx.x * RPB + wid * RPW;
    const int koff = (lane >> 4) * 8;

    half8 a[2][8];
#pragma unroll
    for (int fr = 0; fr < 2; ++fr) {
        int row = r0 + fr * 16 + (lane & 15);
        if (row >= nNodes) row = nNodes - 1;
        const _Float16* ap = hm + (size_t)row * HM_STRIDE + koff;
#pragma unroll
        for (int ks = 0; ks < 8; ++ks)
            a[fr][ks] = *reinterpret_cast<const half8*>(ap + ks * 32);
    }

    f32x4 acc[2][CF];
#pragma unroll
    for (int fr = 0; fr < 2; ++fr)
#pragma unroll
        for (int c = 0; c < CF; ++c) acc[fr][c] = {0.f, 0.f, 0.f, 0.f};

#pragma unroll
    for (int c = 0; c < CF; ++c) {
        const int brow = c * 16 + (lane & 15);
        const int bswz = (brow & 7) << 3;
#pragma unroll
        for (int ks = 0; ks < 8; ++ks) {
            half8 b = *reinterpret_cast<const half8*>(&bl[brow][(ks * 32 + koff) ^ bswz]);
            acc[0][c] = __builtin_amdgcn_mfma_f32_16x16x32_f16(a[0][ks], b, acc[0][c], 0, 0, 0);
            acc[1][c] = __builtin_amdgcn_mfma_f32_16x16x32_f16(a[1][ks], b, acc[1][c], 0, 0, 0);
        }
    }

    const int ocol = lane & 15;
    const int orow_off = (lane >> 4) << 2;
#pragma unroll
    for (int fr = 0; fr < 2; ++fr) {
        const int rbase = r0 + fr * 16 + orow_off;
#pragma unroll
        for (int c = 0; c < CF; ++c) {
            const int col = c * 16 + ocol;
            const float bv = bias[col];
#pragma unroll
            for (int reg = 0; reg < 4; ++reg) {
                const int row = rbase + reg;
                if (row < nNodes) {
                    float v = acc[fr][c][reg] + bv;
                    if (ACT) v = fmaxf(v, 0.f);
                    if (OUT_FP32) outf[(size_t)row * NCOL + col] = v;
                    else outh[(size_t)row * HM_STRIDE + col] = (_Float16)v;
                }
            }
        }
    }
}

// ================= launch =================

extern "C" void kernel_launch(void* const* d_in, const int* in_sizes, int n_in,
                              void* d_out, int out_size, void* d_ws, size_t ws_size,
                              hipStream_t stream) {
    const float* feat = (const float*)d_in[0];
    const int* src = (const int*)d_in[1];
    const int* dst = (const int*)d_in[2];
    const float* Ws0 = (const float*)d_in[3];
    const float* Wn0 = (const float*)d_in[4];
    const float* b0 = (const float*)d_in[5];
    const float* Ws1 = (const float*)d_in[6];
    const float* Wn1 = (const float*)d_in[7];
    const float* b1 = (const float*)d_in[8];
    const float* Ws2 = (const float*)d_in[9];
    const float* Wn2 = (const float*)d_in[10];
    const float* b2 = (const float*)d_in[11];
    float* out = (float*)d_out;

    auto align_up = [](size_t x) { return (x + 255) & ~(size_t)255; };
    char* w = (char*)d_ws;
    uint_t* histG = (uint_t*)w; w += align_up((size_t)NB_C * 256 * 4);
    uint_t* cbase = (uint_t*)w; w += align_up(257 * 4);
    uint_t* tmp = (uint_t*)w;   w += align_up((size_t)N_EDGES_C * 4);
    int* offs = (int*)w;        w += align_up((size_t)(N_NODES_C + 1) * 4);
    int* ssrc = (int*)w;        w += align_up((size_t)N_EDGES_C * 4);
    _Float16* hm0 = (_Float16*)w; w += align_up((size_t)N_NODES_C * HM_STRIDE * 2);
    _Float16* hm1 = (_Float16*)w; w += align_up((size_t)N_NODES_C * HM_STRIDE * 2);
    _Float16* WT0 = (_Float16*)w; w += align_up((size_t)128 * 256 * 2);
    _Float16* WT1 = (_Float16*)w; w += align_up((size_t)128 * 256 * 2);
    _Float16* WT2 = (_Float16*)w; w += align_up((size_t)64 * 256 * 2);
    _Float16* hm2 = hm0;  // hm0 is dead after GEMM0 reads it

    // ---- CSR build (two-level bucket sort, no global atomics) ----
    p1hist_kernel<<<NB_C, 256, 0, stream>>>(dst, histG, N_EDGES_C);
    p1scan_kernel<<<1, 256, 0, stream>>>(histG, cbase, NB_C);
    p1scatter_kernel<<<NB_C, 256, 0, stream>>>(src, dst, histG, tmp, N_EDGES_C);
    p2_kernel<<<NB_C, 256, 0, stream>>>(tmp, cbase, offs, ssrc);

    // ---- converts (features + all weights, one launch) ----
    const int convBlocks = (N_NODES_C * K_FEAT / 4 + 81920 + 255) / 256;
    convert_kernel<<<convBlocks, 256, 0, stream>>>(
        feat, hm0, Ws0, Wn0, Ws1, Wn1, Ws2, Wn2, WT0, WT1, WT2);

    const int meanBlocks = (N_NODES_C * 64 + 255) / 256;
    const int gemmBlocks = (N_NODES_C + 127) / 128;  // 391

    // ---- layer 0 ----
    mean_kernel<<<meanBlocks, 256, 0, stream>>>(hm0, offs, ssrc);
    sage_mfma<128, true, false><<<gemmBlocks, 256, 0, stream>>>(
        hm0, WT0, b0, nullptr, hm1, N_NODES_C);

    // ---- layer 1 ----
    mean_kernel<<<meanBlocks, 256, 0, stream>>>(hm1, offs, ssrc);
    sage_mfma<128, true, false><<<gemmBlocks, 256, 0, stream>>>(
        hm1, WT1, b1, nullptr, hm2, N_NODES_C);

    // ---- layer 2 ----
    mean_kernel<<<meanBlocks, 256, 0, stream>>>(hm2, offs, ssrc);
    sage_mfma<64, false, true><<<gemmBlocks, 256, 0, stream>>>(
        hm2, WT2, b2, out, nullptr, N_NODES_C);
}

// Round 9
// 173.334 us; speedup vs baseline: 1.3039x; 1.3039x over previous
//
#include <hip/hip_runtime.h>
#include <hip/hip_fp16.h>

#define N_NODES_C 50000
#define N_EDGES_C 800000
#define K_FEAT 128
#define HM_STRIDE 256  // [h(128) | mean(128)] fp16 per node
#define NB_C 196       // coarse buckets / edge blocks (196*4096 >= 800000; 50000 <= 196*256)

typedef unsigned int uint_t;
typedef _Float16 half8 __attribute__((ext_vector_type(8)));
typedef _Float16 half4 __attribute__((ext_vector_type(4)));
typedef float f32x4 __attribute__((ext_vector_type(4)));

// ================= CSR build via 2-level bucket sort (NO global atomics) =================
// Level 1: coarse bucket = dst>>8 (256 nodes per bucket, 196 used).
// Level 2: within bucket, fine bin = dst&255; global CSR offsets fall out directly.

// P1a: per-block coarse histogram (LDS atomics only).
__global__ __launch_bounds__(256) void p1hist_kernel(const int* __restrict__ dst,
                                                     uint_t* __restrict__ histG, int E) {
    __shared__ uint_t hist[256];
    const int t = threadIdx.x, b = blockIdx.x;
    hist[t] = 0;
    __syncthreads();
    const int base = b * 4096;
#pragma unroll
    for (int j = 0; j < 16; ++j) {
        int idx = base + t + j * 256;
        if (idx < E) atomicAdd(&hist[((uint_t)dst[idx]) >> 8], 1u);
    }
    __syncthreads();
    histG[b * 256 + t] = hist[t];
}

// P1b: single block. Column scan over blocks, register-batched (28 loads in flight).
// histG[b*256+t] -> per-(block,bin) base RELATIVE to bin start; cbase[t] = bin start.
__global__ __launch_bounds__(256) void p1scan_kernel(uint_t* __restrict__ histG,
                                                     uint_t* __restrict__ cbase) {
    const int t = threadIdx.x;
    uint_t run = 0;
    // 196 = 7 chunks x 28; loads within a chunk are independent & coalesced across t.
    for (int bb = 0; bb < NB_C; bb += 28) {
        uint_t vals[28];
#pragma unroll
        for (int j = 0; j < 28; ++j) vals[j] = histG[(size_t)(bb + j) * 256 + t];
#pragma unroll
        for (int j = 0; j < 28; ++j) {
            uint_t x = vals[j];
            vals[j] = run;
            run += x;
        }
#pragma unroll
        for (int j = 0; j < 28; ++j) histG[(size_t)(bb + j) * 256 + t] = vals[j];
    }
    // run = total for bin t; block-wide exclusive scan -> cbase
    const int lane = t & 63, wid = t >> 6;
    uint_t x = run;
#pragma unroll
    for (int off = 1; off < 64; off <<= 1) {
        uint_t y = __shfl_up(x, off, 64);
        if (lane >= off) x += y;
    }
    __shared__ uint_t wsum[4];
    if (lane == 63) wsum[wid] = x;
    __syncthreads();
    uint_t wpre = 0;
#pragma unroll
    for (int w = 0; w < 4; ++w)
        if (w < wid) wpre += wsum[w];
    uint_t incl = wpre + x;
    cbase[t] = incl - run;
    if (t == 255) cbase[256] = incl;  // == E
}

// P1c: scatter packed (fine<<16 | src) into coarse-bucket-contiguous tmp via LDS cursors.
// Cursor = per-(block,bin) relative base + cbase[bin].
__global__ __launch_bounds__(256) void p1scatter_kernel(const int* __restrict__ src,
                                                        const int* __restrict__ dst,
                                                        const uint_t* __restrict__ histG,
                                                        const uint_t* __restrict__ cbase,
                                                        uint_t* __restrict__ tmp, int E) {
    __shared__ uint_t cur[256];
    const int t = threadIdx.x, b = blockIdx.x;
    cur[t] = histG[b * 256 + t] + cbase[t];
    __syncthreads();
    const int base = b * 4096;
#pragma unroll
    for (int j = 0; j < 16; ++j) {
        int idx = base + t + j * 256;
        if (idx < E) {
            uint_t d = (uint_t)dst[idx];
            uint_t s = (uint_t)src[idx];  // < 50000 < 2^16
            uint_t slot = atomicAdd(&cur[d >> 8], 1u);
            tmp[slot] = ((d & 255u) << 16) | s;
        }
    }
}

// P2: one block per coarse bucket. Fine histogram + LDS scan -> offs; LDS-cursor scatter -> ssrc.
__global__ __launch_bounds__(256) void p2_kernel(const uint_t* __restrict__ tmp,
                                                 const uint_t* __restrict__ cbase,
                                                 int* __restrict__ offs, int* __restrict__ ssrc) {
    __shared__ uint_t hist[256];
    __shared__ uint_t cur[256];
    __shared__ uint_t wsum[4];
    const int t = threadIdx.x, c = blockIdx.x;
    const uint_t cb = cbase[c], ce = cbase[c + 1];
    hist[t] = 0;
    __syncthreads();
    for (uint_t i = cb + t; i < ce; i += 256) atomicAdd(&hist[tmp[i] >> 16], 1u);
    __syncthreads();
    const uint_t v = hist[t];
    const int lane = t & 63, wid = t >> 6;
    uint_t x = v;
#pragma unroll
    for (int off = 1; off < 64; off <<= 1) {
        uint_t y = __shfl_up(x, off, 64);
        if (lane >= off) x += y;
    }
    if (lane == 63) wsum[wid] = x;
    __syncthreads();
    uint_t wpre = 0;
#pragma unroll
    for (int w = 0; w < 4; ++w)
        if (w < wid) wpre += wsum[w];
    const uint_t excl = wpre + x - v;
    const int node = c * 256 + t;
    if (node < N_NODES_C) offs[node] = (int)(cb + excl);
    if (c == 0 && t == 0) offs[N_NODES_C] = N_EDGES_C;
    cur[t] = excl;
    __syncthreads();
    for (uint_t i = cb + t; i < ce; i += 256) {
        uint_t p = tmp[i];
        uint_t slot = cb + atomicAdd(&cur[p >> 16], 1u);
        ssrc[slot] = (int)(p & 0xFFFFu);
    }
}

// ================= fused convert: features->fp16 hm0 h-part, weights->fp16 transposed =====
// WT[c][k] = Wcat[k][c]; Wcat rows 0..127 = Ws, 128..255 = Wn.

__global__ __launch_bounds__(256) void convert_kernel(
    const float* __restrict__ feat, _Float16* __restrict__ hm0,
    const float* __restrict__ Ws0, const float* __restrict__ Wn0,
    const float* __restrict__ Ws1, const float* __restrict__ Wn1,
    const float* __restrict__ Ws2, const float* __restrict__ Wn2,
    _Float16* __restrict__ WT0, _Float16* __restrict__ WT1, _Float16* __restrict__ WT2) {
    const int i = blockIdx.x * 256 + threadIdx.x;
    const int n4 = N_NODES_C * K_FEAT / 4;  // 1,600,000 float4s
    if (i < n4) {
        float4 v = reinterpret_cast<const float4*>(feat)[i];
        int n = i >> 5, c4 = i & 31;
        half4 o;
        o.x = (_Float16)v.x; o.y = (_Float16)v.y; o.z = (_Float16)v.z; o.w = (_Float16)v.w;
        *reinterpret_cast<half4*>(hm0 + (size_t)n * HM_STRIDE + c4 * 4) = o;
    } else {
        int idx = i - n4;
        if (idx >= 81920) return;
        const float* Ws;
        const float* Wn;
        _Float16* WT;
        int ncol;
        if (idx < 32768) { Ws = Ws0; Wn = Wn0; WT = WT0; ncol = 128; }
        else if (idx < 65536) { idx -= 32768; Ws = Ws1; Wn = Wn1; WT = WT1; ncol = 128; }
        else { idx -= 65536; Ws = Ws2; Wn = Wn2; WT = WT2; ncol = 64; }
        int k = idx & 255, c = idx >> 8;
        float v = (k < 128) ? Ws[(size_t)k * ncol + c] : Wn[(size_t)(k - 128) * ncol + c];
        WT[(size_t)c * 256 + k] = (_Float16)v;
    }
}

// ================= mean aggregation: one wave per node, 4 edge-rows per vmem instr ========

__global__ void mean_kernel(_Float16* __restrict__ hm, const int* __restrict__ offs,
                            const int* __restrict__ ssrc) {
    const int node = (int)((blockIdx.x * blockDim.x + threadIdx.x) >> 6);
    const int lane = threadIdx.x & 63;
    if (node >= N_NODES_C) return;
    const int beg = offs[node], end = offs[node + 1];
    const int g = lane >> 4;
    const int cb = (lane & 15) * 8;
    const _Float16* base = hm + cb;

    float accA[8] = {0.f, 0.f, 0.f, 0.f, 0.f, 0.f, 0.f, 0.f};
    float accB[8] = {0.f, 0.f, 0.f, 0.f, 0.f, 0.f, 0.f, 0.f};

    int e = beg;
    for (; e + 8 <= end; e += 8) {
        const int s0 = ssrc[e + g];
        const int s1 = ssrc[e + 4 + g];
        half8 v0 = *reinterpret_cast<const half8*>(base + (size_t)s0 * HM_STRIDE);
        half8 v1 = *reinterpret_cast<const half8*>(base + (size_t)s1 * HM_STRIDE);
#pragma unroll
        for (int j = 0; j < 8; ++j) accA[j] += (float)v0[j];
#pragma unroll
        for (int j = 0; j < 8; ++j) accB[j] += (float)v1[j];
    }
    for (; e + 4 <= end; e += 4) {
        const int s0 = ssrc[e + g];
        half8 v0 = *reinterpret_cast<const half8*>(base + (size_t)s0 * HM_STRIDE);
#pragma unroll
        for (int j = 0; j < 8; ++j) accA[j] += (float)v0[j];
    }
    if (e < end) {
        const bool valid = (e + g) < end;
        const int s0 = valid ? ssrc[e + g] : ssrc[beg];
        half8 v0 = *reinterpret_cast<const half8*>(base + (size_t)s0 * HM_STRIDE);
        if (valid) {
#pragma unroll
            for (int j = 0; j < 8; ++j) accB[j] += (float)v0[j];
        }
    }

    const float inv = (end > beg) ? 1.0f / (float)(end - beg) : 0.f;
    half8 o;
#pragma unroll
    for (int j = 0; j < 8; ++j) {
        float x = accA[j] + accB[j];
        x += __shfl_xor(x, 16, 64);
        x += __shfl_xor(x, 32, 64);
        o[j] = (_Float16)(x * inv);
    }
    if (lane < 16)
        *reinterpret_cast<half8*>(hm + (size_t)node * HM_STRIDE + 128 + cb) = o;
}

// ================= MFMA GEMM: out = act(hm @ Wcat + b), K=256 =================
// Block: 256 threads (4 waves), 128 rows. WT staged in LDS (XOR-swizzled).
// All 16 A-frags preloaded to registers, then pure LDS+MFMA.
// C/D mapping: col=lane&15, row=(lane>>4)*4+reg (m89-verified).

template <int NCOL, bool ACT, bool OUT_FP32>
__global__ __launch_bounds__(256) void sage_mfma(
    const _Float16* __restrict__ hm,  // [n][256]
    const _Float16* __restrict__ WT,  // [NCOL][256]
    const float* __restrict__ bias,
    float* __restrict__ outf,         // OUT_FP32: [n][NCOL]
    _Float16* __restrict__ outh,      // else: next layer's hm, h-part
    int nNodes) {
    constexpr int CF = NCOL / 16;
    constexpr int RPW = 32;
    constexpr int RPB = 128;

    __shared__ _Float16 bl[NCOL][256];

    const int t = threadIdx.x;
#pragma unroll
    for (int it = 0; it < NCOL * 32 / 256; ++it) {
        int f = t + it * 256;
        int row = f >> 5, c8 = f & 31;
        half8 v = *reinterpret_cast<const half8*>(WT + (size_t)row * 256 + c8 * 8);
        int col = (c8 * 8) ^ ((row & 7) << 3);
        *reinterpret_cast<half8*>(&bl[row][col]) = v;
    }
    __syncthreads();

    const int wid = t >> 6;
    const int lane = t & 63;
    const int r0 = blockIdx.x * RPB + wid * RPW;
    const int koff = (lane >> 4) * 8;

    half8 a[2][8];
#pragma unroll
    for (int fr = 0; fr < 2; ++fr) {
        int row = r0 + fr * 16 + (lane & 15);
        if (row >= nNodes) row = nNodes - 1;
        const _Float16* ap = hm + (size_t)row * HM_STRIDE + koff;
#pragma unroll
        for (int ks = 0; ks < 8; ++ks)
            a[fr][ks] = *reinterpret_cast<const half8*>(ap + ks * 32);
    }

    f32x4 acc[2][CF];
#pragma unroll
    for (int fr = 0; fr < 2; ++fr)
#pragma unroll
        for (int c = 0; c < CF; ++c) acc[fr][c] = {0.f, 0.f, 0.f, 0.f};

#pragma unroll
    for (int c = 0; c < CF; ++c) {
        const int brow = c * 16 + (lane & 15);
        const int bswz = (brow & 7) << 3;
#pragma unroll
        for (int ks = 0; ks < 8; ++ks) {
            half8 b = *reinterpret_cast<const half8*>(&bl[brow][(ks * 32 + koff) ^ bswz]);
            acc[0][c] = __builtin_amdgcn_mfma_f32_16x16x32_f16(a[0][ks], b, acc[0][c], 0, 0, 0);
            acc[1][c] = __builtin_amdgcn_mfma_f32_16x16x32_f16(a[1][ks], b, acc[1][c], 0, 0, 0);
        }
    }

    const int ocol = lane & 15;
    const int orow_off = (lane >> 4) << 2;
#pragma unroll
    for (int fr = 0; fr < 2; ++fr) {
        const int rbase = r0 + fr * 16 + orow_off;
#pragma unroll
        for (int c = 0; c < CF; ++c) {
            const int col = c * 16 + ocol;
            const float bv = bias[col];
#pragma unroll
            for (int reg = 0; reg < 4; ++reg) {
                const int row = rbase + reg;
                if (row < nNodes) {
                    float v = acc[fr][c][reg] + bv;
                    if (ACT) v = fmaxf(v, 0.f);
                    if (OUT_FP32) outf[(size_t)row * NCOL + col] = v;
                    else outh[(size_t)row * HM_STRIDE + col] = (_Float16)v;
                }
            }
        }
    }
}

// ================= launch =================

extern "C" void kernel_launch(void* const* d_in, const int* in_sizes, int n_in,
                              void* d_out, int out_size, void* d_ws, size_t ws_size,
                              hipStream_t stream) {
    const float* feat = (const float*)d_in[0];
    const int* src = (const int*)d_in[1];
    const int* dst = (const int*)d_in[2];
    const float* Ws0 = (const float*)d_in[3];
    const float* Wn0 = (const float*)d_in[4];
    const float* b0 = (const float*)d_in[5];
    const float* Ws1 = (const float*)d_in[6];
    const float* Wn1 = (const float*)d_in[7];
    const float* b1 = (const float*)d_in[8];
    const float* Ws2 = (const float*)d_in[9];
    const float* Wn2 = (const float*)d_in[10];
    const float* b2 = (const float*)d_in[11];
    float* out = (float*)d_out;

    auto align_up = [](size_t x) { return (x + 255) & ~(size_t)255; };
    char* w = (char*)d_ws;
    uint_t* histG = (uint_t*)w; w += align_up((size_t)NB_C * 256 * 4);
    uint_t* cbase = (uint_t*)w; w += align_up(257 * 4);
    uint_t* tmp = (uint_t*)w;   w += align_up((size_t)N_EDGES_C * 4);
    int* offs = (int*)w;        w += align_up((size_t)(N_NODES_C + 1) * 4);
    int* ssrc = (int*)w;        w += align_up((size_t)N_EDGES_C * 4);
    _Float16* hm0 = (_Float16*)w; w += align_up((size_t)N_NODES_C * HM_STRIDE * 2);
    _Float16* hm1 = (_Float16*)w; w += align_up((size_t)N_NODES_C * HM_STRIDE * 2);
    _Float16* WT0 = (_Float16*)w; w += align_up((size_t)128 * 256 * 2);
    _Float16* WT1 = (_Float16*)w; w += align_up((size_t)128 * 256 * 2);
    _Float16* WT2 = (_Float16*)w; w += align_up((size_t)64 * 256 * 2);
    _Float16* hm2 = hm0;  // hm0 is dead after GEMM0 reads it

    // ---- CSR build (two-level bucket sort, no global atomics) ----
    p1hist_kernel<<<NB_C, 256, 0, stream>>>(dst, histG, N_EDGES_C);
    p1scan_kernel<<<1, 256, 0, stream>>>(histG, cbase);
    p1scatter_kernel<<<NB_C, 256, 0, stream>>>(src, dst, histG, cbase, tmp, N_EDGES_C);
    p2_kernel<<<NB_C, 256, 0, stream>>>(tmp, cbase, offs, ssrc);

    // ---- converts (features + all weights, one launch) ----
    const int convBlocks = (N_NODES_C * K_FEAT / 4 + 81920 + 255) / 256;
    convert_kernel<<<convBlocks, 256, 0, stream>>>(
        feat, hm0, Ws0, Wn0, Ws1, Wn1, Ws2, Wn2, WT0, WT1, WT2);

    const int meanBlocks = (N_NODES_C * 64 + 255) / 256;
    const int gemmBlocks = (N_NODES_C + 127) / 128;  // 391

    // ---- layer 0 ----
    mean_kernel<<<meanBlocks, 256, 0, stream>>>(hm0, offs, ssrc);
    sage_mfma<128, true, false><<<gemmBlocks, 256, 0, stream>>>(
        hm0, WT0, b0, nullptr, hm1, N_NODES_C);

    // ---- layer 1 ----
    mean_kernel<<<meanBlocks, 256, 0, stream>>>(hm1, offs, ssrc);
    sage_mfma<128, true, false><<<gemmBlocks, 256, 0, stream>>>(
        hm1, WT1, b1, nullptr, hm2, N_NODES_C);

    // ---- layer 2 ----
    mean_kernel<<<meanBlocks, 256, 0, stream>>>(hm2, offs, ssrc);
    sage_mfma<64, false, true><<<gemmBlocks, 256, 0, stream>>>(
        hm2, WT2, b2, out, nullptr, N_NODES_C);
}